// Round 1
// baseline (7911.893 us; speedup 1.0000x reference)
//
#include <hip/hip_runtime.h>

#define N_NODES 10000
#define H_DIM   128
#define E_EDGES 160000
#define R_DIM   32
#define IN_DIM  34

__device__ __forceinline__ float silu_f(float z) {
    return z / (1.0f + __expf(-z));
}

// ---------------------------------------------------------------------------
// Kernel 1: per-node prep.
// Xn = X/(||X||^2+1); decompose -> 9 comps [I, a0,a1,a2, s00,s01,s02,s11,s12];
// channel-mix with Wt0 (I), Wt1 (A), Wt2 (S); write Y comps to [N][H][12].
// 4 nodes per 256-thread block.
// ---------------------------------------------------------------------------
__global__ __launch_bounds__(256) void k_prep(
    const float* __restrict__ X,
    const float* __restrict__ Wt0, const float* __restrict__ Wt1,
    const float* __restrict__ Wt2,
    float* __restrict__ Y)
{
    __shared__ __align__(16) float dec[4 * 128 * 12];
    const int n0  = blockIdx.x * 4;
    const int tid = threadIdx.x;

    for (int idx = tid; idx < 512; idx += 256) {
        const int nl = idx >> 7, h = idx & 127;
        const float* t = X + ((size_t)((n0 + nl) * H_DIM + h)) * 9;
        float T[9];
#pragma unroll
        for (int i = 0; i < 9; i++) T[i] = t[i];
        float nrm = 0.f;
#pragma unroll
        for (int i = 0; i < 9; i++) nrm = fmaf(T[i], T[i], nrm);
        const float inv = 1.0f / (nrm + 1.0f);
#pragma unroll
        for (int i = 0; i < 9; i++) T[i] *= inv;
        const float I = (T[0] + T[4] + T[8]) * (1.0f / 3.0f);
        float* d = dec + idx * 12;
        d[0] = I;
        d[1] = 0.5f * (T[7] - T[5]);   // a0 = A21
        d[2] = 0.5f * (T[2] - T[6]);   // a1 = A02
        d[3] = 0.5f * (T[3] - T[1]);   // a2 = A10
        d[4] = T[0] - I;               // s00
        d[5] = 0.5f * (T[1] + T[3]);   // s01
        d[6] = 0.5f * (T[2] + T[6]);   // s02
        d[7] = T[4] - I;               // s11
        d[8] = 0.5f * (T[5] + T[7]);   // s12
    }
    __syncthreads();

    for (int idx = tid; idx < 512; idx += 256) {
        const int nl = idx >> 7, o = idx & 127;
        float acc[9];
#pragma unroll
        for (int c = 0; c < 9; c++) acc[c] = 0.f;
        const float* d = dec + nl * 128 * 12;
#pragma unroll 4
        for (int h = 0; h < 128; h++) {
            const float w0 = Wt0[o * 128 + h];
            const float w1 = Wt1[o * 128 + h];
            const float w2 = Wt2[o * 128 + h];
            const float* dh = d + h * 12;
            acc[0] = fmaf(dh[0], w0, acc[0]);
            acc[1] = fmaf(dh[1], w1, acc[1]);
            acc[2] = fmaf(dh[2], w1, acc[2]);
            acc[3] = fmaf(dh[3], w1, acc[3]);
            acc[4] = fmaf(dh[4], w2, acc[4]);
            acc[5] = fmaf(dh[5], w2, acc[5]);
            acc[6] = fmaf(dh[6], w2, acc[6]);
            acc[7] = fmaf(dh[7], w2, acc[7]);
            acc[8] = fmaf(dh[8], w2, acc[8]);
        }
        float* y = Y + ((size_t)((n0 + nl) * H_DIM + o)) * 12;
#pragma unroll
        for (int c = 0; c < 9; c++) y[c] = acc[c];
    }
}

// ---------------------------------------------------------------------------
// Kernel 2: fused edge MLP + message passing. 32 edges per 256-thread block.
// ---------------------------------------------------------------------------
__global__ __launch_bounds__(256) void k_edge(
    const float* __restrict__ EA, const float* __restrict__ CH,
    const float* __restrict__ EW, const int*   __restrict__ EI,
    const float* __restrict__ W1, const float* __restrict__ b1,
    const float* __restrict__ W2, const float* __restrict__ b2,
    const float* __restrict__ W3, const float* __restrict__ b3,
    const float* __restrict__ Y,  float* __restrict__ MSG)
{
    __shared__ __align__(16) float sIn[32 * 35];
    __shared__ __align__(16) float sH1[32 * 132];
    __shared__ __align__(16) float sH2[32 * 260];
    __shared__ __align__(16) float sXc[32 * 132];
    __shared__ float sC[32];
    __shared__ int   sS[32], sD[32];

    const int e0  = blockIdx.x * 32;
    const int tid = threadIdx.x;

    {   // edge_attr: 32 edges x 32 floats, contiguous -> one float4 per thread
        const float4 v = ((const float4*)(EA + (size_t)e0 * R_DIM))[tid];
        const int e = tid >> 3;
        const int k = (tid & 7) * 4;
        float* p = sIn + e * 35 + k;
        p[0] = v.x; p[1] = v.y; p[2] = v.z; p[3] = v.w;
    }
    if (tid < 32) {
        const int e = tid;
        const int s = EI[e0 + e];
        const int d = EI[E_EDGES + e0 + e];
        sS[e] = s; sD[e] = d;
        sIn[e * 35 + 32] = CH[s];
        sIn[e * 35 + 33] = CH[d];
        const float w = EW[e0 + e];
        sC[e] = (w < 5.0f) ? 0.5f * (__cosf(0.62831853071795864769f * w) + 1.0f)
                           : 0.0f;
    }
    __syncthreads();

    const int e  = tid & 31;
    const int og = tid >> 5;   // 8 output groups

    // ---- layer 1: 34 -> 128 (16 outputs/thread) ----
    {
        float acc[16];
#pragma unroll
        for (int j = 0; j < 16; j++) acc[j] = b1[og * 16 + j];
        for (int k = 0; k < IN_DIM; k++) {
            const float v = sIn[e * 35 + k];
#pragma unroll
            for (int j = 0; j < 16; j++)
                acc[j] = fmaf(v, W1[(og * 16 + j) * IN_DIM + k], acc[j]);
        }
#pragma unroll
        for (int j = 0; j < 16; j++)
            sH1[e * 132 + og * 16 + j] = silu_f(acc[j]);
    }
    __syncthreads();

    // ---- layer 2: 128 -> 256 (32 outputs/thread) ----
    {
        float acc[32];
#pragma unroll
        for (int j = 0; j < 32; j++) acc[j] = b2[og * 32 + j];
        for (int hq = 0; hq < 32; hq++) {
            const float4 v = *(const float4*)&sH1[e * 132 + hq * 4];
#pragma unroll
            for (int j = 0; j < 32; j++) {
                const float4 w =
                    *(const float4*)&W2[(size_t)(og * 32 + j) * 128 + hq * 4];
                acc[j] = fmaf(v.x, w.x,
                         fmaf(v.y, w.y,
                         fmaf(v.z, w.z,
                         fmaf(v.w, w.w, acc[j]))));
            }
        }
#pragma unroll
        for (int j = 0; j < 32; j++)
            sH2[e * 260 + og * 32 + j] = silu_f(acc[j]);
    }
    __syncthreads();

    // ---- layer 3 (per class) + message passing ----
    for (int c = 0; c < 3; c++) {
        {
            float acc[16];
#pragma unroll
            for (int j = 0; j < 16; j++) acc[j] = b3[c * 128 + og * 16 + j];
            for (int hq = 0; hq < 64; hq++) {
                const float4 v = *(const float4*)&sH2[e * 260 + hq * 4];
#pragma unroll
                for (int j = 0; j < 16; j++) {
                    const float4 w = *(const float4*)
                        &W3[(size_t)(c * 128 + og * 16 + j) * 256 + hq * 4];
                    acc[j] = fmaf(v.x, w.x,
                             fmaf(v.y, w.y,
                             fmaf(v.z, w.z,
                             fmaf(v.w, w.w, acc[j]))));
                }
            }
            const float cc = sC[e];
#pragma unroll
            for (int j = 0; j < 16; j++)
                sXc[e * 132 + og * 16 + j] = silu_f(acc[j]) * cc;
        }
        __syncthreads();
        {
            const int h  = tid & 127;
            const int eh = tid >> 7;
#pragma unroll 4
            for (int i = 0; i < 16; i++) {
                const int ee = (eh << 4) | i;
                const int s = sS[ee], d = sD[ee];
                const float xv = sXc[ee * 132 + h];
                const float* yb = Y   + ((size_t)(d * H_DIM + h)) * 12;
                float*       mb = MSG + ((size_t)(s * H_DIM + h)) * 12;
                if (c == 0) {
                    atomicAdd(mb + 0, xv * yb[0]);
                } else if (c == 1) {
                    atomicAdd(mb + 1, xv * yb[1]);
                    atomicAdd(mb + 2, xv * yb[2]);
                    atomicAdd(mb + 3, xv * yb[3]);
                } else {
                    atomicAdd(mb + 4, xv * yb[4]);
                    atomicAdd(mb + 5, xv * yb[5]);
                    atomicAdd(mb + 6, xv * yb[6]);
                    atomicAdd(mb + 7, xv * yb[7]);
                    atomicAdd(mb + 8, xv * yb[8]);
                }
            }
        }
        __syncthreads();
    }
}

// ---------------------------------------------------------------------------
// Kernel 3: per-node finish.
// M = msg*Y + Y*msg; decompose; /(norm+1); mix Wt3/4/5; out = Xn + dX + dX*dX.
// ---------------------------------------------------------------------------
__global__ __launch_bounds__(256) void k_finish(
    const float* __restrict__ X,
    const float* __restrict__ Y, const float* __restrict__ MSG,
    const float* __restrict__ Wt3, const float* __restrict__ Wt4,
    const float* __restrict__ Wt5,
    float* __restrict__ out)
{
    __shared__ __align__(16) float dec[4 * 128 * 12];
    const int n0  = blockIdx.x * 4;
    const int tid = threadIdx.x;

    for (int idx = tid; idx < 512; idx += 256) {
        const size_t base =
            ((size_t)((n0 + (idx >> 7)) * H_DIM + (idx & 127))) * 12;
        const float* y = Y + base;
        const float* m = MSG + base;
        float Yt[9], G[9];
        {
            const float I = y[0], a0 = y[1], a1 = y[2], a2 = y[3];
            const float s00 = y[4], s01 = y[5], s02 = y[6], s11 = y[7], s12 = y[8];
            const float s22 = -s00 - s11;
            Yt[0] = I + s00; Yt[1] = s01 - a2; Yt[2] = s02 + a1;
            Yt[3] = s01 + a2; Yt[4] = I + s11; Yt[5] = s12 - a0;
            Yt[6] = s02 - a1; Yt[7] = s12 + a0; Yt[8] = I + s22;
        }
        {
            const float I = m[0], a0 = m[1], a1 = m[2], a2 = m[3];
            const float s00 = m[4], s01 = m[5], s02 = m[6], s11 = m[7], s12 = m[8];
            const float s22 = -s00 - s11;
            G[0] = I + s00; G[1] = s01 - a2; G[2] = s02 + a1;
            G[3] = s01 + a2; G[4] = I + s11; G[5] = s12 - a0;
            G[6] = s02 - a1; G[7] = s12 + a0; G[8] = I + s22;
        }
        float M[9];
#pragma unroll
        for (int i = 0; i < 3; i++)
#pragma unroll
            for (int j = 0; j < 3; j++) {
                float acc = 0.f;
#pragma unroll
                for (int k = 0; k < 3; k++)
                    acc += G[i * 3 + k] * Yt[k * 3 + j]
                         + Yt[i * 3 + k] * G[k * 3 + j];
                M[i * 3 + j] = acc;
            }
        const float I2 = (M[0] + M[4] + M[8]) * (1.0f / 3.0f);
        const float a0 = 0.5f * (M[7] - M[5]);
        const float a1 = 0.5f * (M[2] - M[6]);
        const float a2 = 0.5f * (M[3] - M[1]);
        const float s00 = M[0] - I2, s11 = M[4] - I2;
        const float s01 = 0.5f * (M[1] + M[3]);
        const float s02 = 0.5f * (M[2] + M[6]);
        const float s12 = 0.5f * (M[5] + M[7]);
        const float s22 = -s00 - s11;
        const float nrm = 2.f * (a0 * a0 + a1 * a1 + a2 * a2)
                        + (s00 * s00 + s11 * s11 + s22 * s22)
                        + 2.f * (s01 * s01 + s02 * s02 + s12 * s12)
                        + 3.f * I2 * I2;
        const float inv = 1.0f / (nrm + 1.0f);
        float* dd = dec + idx * 12;
        dd[0] = I2 * inv;  dd[1] = a0 * inv;  dd[2] = a1 * inv;  dd[3] = a2 * inv;
        dd[4] = s00 * inv; dd[5] = s01 * inv; dd[6] = s02 * inv;
        dd[7] = s11 * inv; dd[8] = s12 * inv;
    }
    __syncthreads();

    for (int idx = tid; idx < 512; idx += 256) {
        const int nl = idx >> 7, o = idx & 127;
        float acc[9];
#pragma unroll
        for (int c = 0; c < 9; c++) acc[c] = 0.f;
        const float* d = dec + nl * 128 * 12;
#pragma unroll 4
        for (int h = 0; h < 128; h++) {
            const float w3 = Wt3[o * 128 + h];
            const float w4 = Wt4[o * 128 + h];
            const float w5 = Wt5[o * 128 + h];
            const float* dh = d + h * 12;
            acc[0] = fmaf(dh[0], w3, acc[0]);
            acc[1] = fmaf(dh[1], w4, acc[1]);
            acc[2] = fmaf(dh[2], w4, acc[2]);
            acc[3] = fmaf(dh[3], w4, acc[3]);
            acc[4] = fmaf(dh[4], w5, acc[4]);
            acc[5] = fmaf(dh[5], w5, acc[5]);
            acc[6] = fmaf(dh[6], w5, acc[6]);
            acc[7] = fmaf(dh[7], w5, acc[7]);
            acc[8] = fmaf(dh[8], w5, acc[8]);
        }
        float D[9];
        {
            const float I = acc[0], a0 = acc[1], a1 = acc[2], a2 = acc[3];
            const float s00 = acc[4], s01 = acc[5], s02 = acc[6];
            const float s11 = acc[7], s12 = acc[8];
            const float s22 = -s00 - s11;
            D[0] = I + s00; D[1] = s01 - a2; D[2] = s02 + a1;
            D[3] = s01 + a2; D[4] = I + s11; D[5] = s12 - a0;
            D[6] = s02 - a1; D[7] = s12 + a0; D[8] = I + s22;
        }
        const size_t xbase = ((size_t)((n0 + nl) * H_DIM + o)) * 9;
        float T[9];
#pragma unroll
        for (int i = 0; i < 9; i++) T[i] = X[xbase + i];
        float nrm = 0.f;
#pragma unroll
        for (int i = 0; i < 9; i++) nrm = fmaf(T[i], T[i], nrm);
        const float inv = 1.0f / (nrm + 1.0f);
        float* op = out + xbase;
#pragma unroll
        for (int i = 0; i < 3; i++)
#pragma unroll
            for (int j = 0; j < 3; j++) {
                float dd2 = 0.f;
#pragma unroll
                for (int k = 0; k < 3; k++)
                    dd2 = fmaf(D[i * 3 + k], D[k * 3 + j], dd2);
                op[i * 3 + j] = T[i * 3 + j] * inv + D[i * 3 + j] + dd2;
            }
    }
}

// ---------------------------------------------------------------------------
extern "C" void kernel_launch(void* const* d_in, const int* in_sizes, int n_in,
                              void* d_out, int out_size, void* d_ws, size_t ws_size,
                              hipStream_t stream)
{
    const float* X   = (const float*)d_in[0];
    const float* CH  = (const float*)d_in[1];
    const float* EA  = (const float*)d_in[2];
    const float* EW  = (const float*)d_in[3];
    const float* W1  = (const float*)d_in[4];
    const float* b1  = (const float*)d_in[5];
    const float* W2  = (const float*)d_in[6];
    const float* b2  = (const float*)d_in[7];
    const float* W3  = (const float*)d_in[8];
    const float* b3  = (const float*)d_in[9];
    const float* Wt0 = (const float*)d_in[10];
    const float* Wt1 = (const float*)d_in[11];
    const float* Wt2 = (const float*)d_in[12];
    const float* Wt3 = (const float*)d_in[13];
    const float* Wt4 = (const float*)d_in[14];
    const float* Wt5 = (const float*)d_in[15];
    const int*   EI  = (const int*)d_in[16];
    float* out = (float*)d_out;

    float* Ybuf = (float*)d_ws;                       // [N][H][12]
    float* MSG  = Ybuf + (size_t)N_NODES * H_DIM * 12; // [N][H][12]

    hipMemsetAsync(MSG, 0, (size_t)N_NODES * H_DIM * 12 * sizeof(float), stream);

    k_prep<<<N_NODES / 4, 256, 0, stream>>>(X, Wt0, Wt1, Wt2, Ybuf);
    k_edge<<<E_EDGES / 32, 256, 0, stream>>>(EA, CH, EW, EI,
                                             W1, b1, W2, b2, W3, b3,
                                             Ybuf, MSG);
    k_finish<<<N_NODES / 4, 256, 0, stream>>>(X, Ybuf, MSG,
                                              Wt3, Wt4, Wt5, out);
}